// Round 4
// baseline (2727.691 us; speedup 1.0000x reference)
//
#include <hip/hip_runtime.h>

#define T_ 1024
#define B_ 128
#define H_ 128
#define L_ 20
#define G4H_ 512
#define NCH 8              // batch chunks of 16 rows
#define RING 64            // ring depth (steps) per (layer,chunk) channel
#define GRP 4              // publish granularity (steps)
#define FSTRIDE 32         // flag padding: 32 ints = 128 B per flag

typedef _Float16 f16x8 __attribute__((ext_vector_type(8)));
typedef float f32x4 __attribute__((ext_vector_type(4)));

__device__ __forceinline__ float fast_sig(float x) {
  float e = __builtin_amdgcn_exp2f(-1.44269504f * x);
  return __builtin_amdgcn_rcpf(1.0f + e);
}
__device__ __forceinline__ float fast_tanh(float x) {
  float e = __builtin_amdgcn_exp2f(2.88539008f * x);  // e^{2x}
  return 1.0f - 2.0f * __builtin_amdgcn_rcpf(e + 1.0f);
}

__global__ void wconv_kernel(const float* __restrict__ Wih, const float* __restrict__ Whh,
                             _Float16* __restrict__ Wif, _Float16* __restrict__ Whf) {
  int i = blockIdx.x * 256 + threadIdx.x;
  if (i < L_ * G4H_ * H_) {
    Wif[i] = (_Float16)Wih[i];
    Whf[i] = (_Float16)Whh[i];
  }
}

__global__ void emb_kernel(const int* __restrict__ xids, const float* __restrict__ emb,
                           float* __restrict__ out_emb, _Float16* __restrict__ X0) {
  int row = blockIdx.x;       // t*B + b
  int d = threadIdx.x;        // 0..127
  int tok = xids[row];
  float v = emb[(size_t)tok * H_ + d];
  out_emb[(size_t)row * H_ + d] = v;
  X0[(size_t)row * H_ + d] = (_Float16)v;
}

// Persistent wavefront-pipelined LSTM. One block per (layer, batch-chunk).
// R4: raw s_barrier per step (lgkmcnt-only drain; global loads/stores float
// across steps); ring/out publish batched per group from LDS stage; the one
// full __syncthreads per group sits right before the release flag.
__launch_bounds__(512, 2)
__global__ void lstm_persist_kernel(const _Float16* __restrict__ Wif,
                                    const _Float16* __restrict__ Whf,
                                    const float* __restrict__ bih,
                                    const float* __restrict__ bhh,
                                    const _Float16* __restrict__ X0,
                                    _Float16* __restrict__ XR,
                                    float* __restrict__ out_h,
                                    int* __restrict__ rdy) {
  const int l = blockIdx.x >> 3;
  const int chunk = blockIdx.x & 7;
  const int lane = threadIdx.x & 63;
  const int wave = threadIdx.x >> 6;
  const int lr = lane & 15;    // A-frag row / B-frag col / D col
  const int lhi = lane >> 4;   // k-group; D row group
  const int k0 = lhi * 8;
  const int ub = wave * 16;    // hidden slice base

  // ---- weight fragments in registers/AGPRs: W[j=G*128+ub+lr][kt*32+k0..+8]
  f16x8 wi[4][4], wh[4][4];
  float bias[4];
  {
    const _Float16* wip = Wif + (size_t)l * G4H_ * H_;
    const _Float16* whp = Whf + (size_t)l * G4H_ * H_;
#pragma unroll
    for (int G = 0; G < 4; ++G) {
      int j = G * 128 + ub + lr;
      bias[G] = bih[l * G4H_ + j] + bhh[l * G4H_ + j];
#pragma unroll
      for (int kt = 0; kt < 4; ++kt) {
        wi[G][kt] = *(const f16x8*)(wip + (size_t)j * H_ + kt * 32 + k0);
        wh[G][kt] = *(const f16x8*)(whp + (size_t)j * H_ + kt * 32 + k0);
      }
    }
  }

  float cst[4] = {0.f, 0.f, 0.f, 0.f};
  f16x8 hf[4];
#pragma unroll
  for (int kt = 0; kt < 4; ++kt)
#pragma unroll
    for (int i = 0; i < 8; ++i) hf[kt][i] = (_Float16)0.0f;

  __shared__ _Float16 hstage[GRP][16][136];  // h exchange + group publish stage
  __shared__ float ostage[GRP][16][132];     // final-layer fp32 stage

  const size_t tile16 = (size_t)16 * H_;  // 2048 elems = 4KB per step-slice
  const _Float16* ring_in =
      (l > 0) ? XR + (size_t)((l - 1) * NCH + chunk) * RING * tile16 : X0;
  _Float16* ring_out = XR + (size_t)(l * NCH + chunk) * RING * tile16;

  int* rin = rdy + ((l - 1) * NCH + chunk) * FSTRIDE;    // valid only if l>0
  int* rout = rdy + (l * NCH + chunk) * FSTRIDE;
  int* rcons = rdy + ((l + 1) * NCH + chunk) * FSTRIDE;  // valid only if l<L-1

  f16x8 xf[4];
  if (l == 0) {  // step-0 input always available
    const _Float16* xp = X0 + ((size_t)chunk * 16 + lr) * H_ + k0;
#pragma unroll
    for (int kt = 0; kt < 4; ++kt) xf[kt] = *(const f16x8*)(xp + kt * 32);
  }

  for (int tg = 0; tg < T_; tg += GRP) {
    // ---- flag waits (wave 0 only), then full barrier ----
    if (wave == 0) {
      if (l > 0) {  // data-ready: acquire (orders our ring reads after theirs)
        while (__hip_atomic_load(rin, __ATOMIC_ACQUIRE, __HIP_MEMORY_SCOPE_AGENT) < tg + GRP)
          __builtin_amdgcn_s_sleep(2);
      }
      if (l < L_ - 1) {  // backpressure: relaxed (no data flows this way)
        int need = tg + 2 * GRP - RING;
        if (need > 0) {
          while (__hip_atomic_load(rcons, __ATOMIC_RELAXED, __HIP_MEMORY_SCOPE_AGENT) < need)
            __builtin_amdgcn_s_sleep(2);
        }
      }
    }
    __syncthreads();

    if (l > 0) {  // first step of group: load x now that flag passed
      const _Float16* xp = ring_in + (size_t)(tg & (RING - 1)) * tile16 + (size_t)lr * H_ + k0;
#pragma unroll
      for (int kt = 0; kt < 4; ++kt) xf[kt] = *(const f16x8*)(xp + kt * 32);
    }

#pragma unroll
    for (int ti = 0; ti < GRP; ++ti) {
      const int t = tg + ti;

      // h_{t-1} fragments from LDS (written last step, sealed by its barrier)
      if (t > 0) {
        const int ps = (ti + GRP - 1) & (GRP - 1);
#pragma unroll
        for (int kt = 0; kt < 4; ++kt)
          hf[kt] = *(const f16x8*)&hstage[ps][lr][kt * 32 + k0];
      }

      f32x4 ai[4], ah[4];
#pragma unroll
      for (int G = 0; G < 4; ++G) {
        float bv = bias[G];
        ai[G][0] = bv; ai[G][1] = bv; ai[G][2] = bv; ai[G][3] = bv;
        ah[G][0] = 0.f; ah[G][1] = 0.f; ah[G][2] = 0.f; ah[G][3] = 0.f;
      }
      // input GEMM (xf ready; no LDS dep)
#pragma unroll
      for (int kt = 0; kt < 4; ++kt)
#pragma unroll
        for (int G = 0; G < 4; ++G)
          ai[G] = __builtin_amdgcn_mfma_f32_16x16x32_f16(xf[kt], wi[G][kt], ai[G], 0, 0, 0);

      // issue next-step x load NOW: floats across the raw step barrier,
      // consumed at next iteration's input GEMM (compiler inserts the vmcnt).
      const bool pre = (l == 0) ? (t + 1 < T_) : (ti + 1 < GRP);
      if (pre) {
        const _Float16* xp =
            (l == 0) ? X0 + ((size_t)(t + 1) * B_ + chunk * 16 + lr) * H_ + k0
                     : ring_in + (size_t)((t + 1) & (RING - 1)) * tile16 + (size_t)lr * H_ + k0;
#pragma unroll
        for (int kt = 0; kt < 4; ++kt) xf[kt] = *(const f16x8*)(xp + kt * 32);
      }

      // hidden GEMM
#pragma unroll
      for (int kt = 0; kt < 4; ++kt)
#pragma unroll
        for (int G = 0; G < 4; ++G)
          ah[G] = __builtin_amdgcn_mfma_f32_16x16x32_f16(hf[kt], wh[G][kt], ah[G], 0, 0, 0);

      // gates: lane has (b = chunk*16 + lhi*4+r, u = ub+lr)
      float hnew[4];
#pragma unroll
      for (int r = 0; r < 4; ++r) {
        float pi = ai[0][r] + ah[0][r];
        float pf = ai[1][r] + ah[1][r];
        float pg = ai[2][r] + ah[2][r];
        float po = ai[3][r] + ah[3][r];
        float iv = fast_sig(pi);
        float fv = fast_sig(pf);
        float gv = fast_tanh(pg);
        float ov = fast_sig(po);
        float c = fv * cst[r] + iv * gv;
        cst[r] = c;
        hnew[r] = ov * fast_tanh(c);
      }

#pragma unroll
      for (int r = 0; r < 4; ++r) hstage[ti][lhi * 4 + r][ub + lr] = (_Float16)hnew[r];
      if (l == L_ - 1) {
#pragma unroll
        for (int r = 0; r < 4; ++r) ostage[ti][lhi * 4 + r][ub + lr] = hnew[r];
      }

      // raw step barrier: order LDS writes only; globals stay in flight
      asm volatile("s_waitcnt lgkmcnt(0)" ::: "memory");
      __builtin_amdgcn_s_barrier();
      asm volatile("" ::: "memory");
    }

    // ---- group-end publish (cooperative, batched) ----
    const int tid = threadIdx.x;
    const int ti2 = tid >> 7;
    const int rem = tid & 127;
    const int row = rem >> 3;
    const int seg = rem & 7;
    if (l < L_ - 1) {
      // 16 KB: 512 threads x 32 B, contiguous per (ti,row)
      size_t off = (size_t)((tg + ti2) & (RING - 1)) * tile16 + (size_t)row * H_ + seg * 16;
      const f16x8* src = (const f16x8*)&hstage[ti2][row][seg * 16];
      *(f16x8*)(ring_out + off) = src[0];
      *(f16x8*)(ring_out + off + 8) = src[1];
    } else {
      // 32 KB fp32: 512 threads x 64 B
      float* dst = out_h + (((size_t)(tg + ti2) * B_) + chunk * 16 + row) * H_ + seg * 16;
      const float* srcf = &ostage[ti2][row][seg * 16];
#pragma unroll
      for (int q = 0; q < 4; ++q)
        ((f32x4*)dst)[q] = ((const f32x4*)srcf)[q];
    }

    // full barrier: drains each wave's global stores (vmcnt 0) before flag
    __syncthreads();
    if (threadIdx.x == 0) {
      if (l < L_ - 1)
        __hip_atomic_store(rout, tg + GRP, __ATOMIC_RELEASE, __HIP_MEMORY_SCOPE_AGENT);
      else
        __hip_atomic_store(rout, tg + GRP, __ATOMIC_RELAXED, __HIP_MEMORY_SCOPE_AGENT);
    }
  }
}

extern "C" void kernel_launch(void* const* d_in, const int* in_sizes, int n_in,
                              void* d_out, int out_size, void* d_ws, size_t ws_size,
                              hipStream_t stream) {
  const int* xids = (const int*)d_in[0];
  const float* emb = (const float*)d_in[1];
  const float* Wih = (const float*)d_in[2];
  const float* Whh = (const float*)d_in[3];
  const float* bih = (const float*)d_in[4];
  const float* bhh = (const float*)d_in[5];
  float* out = (float*)d_out;
  float* out_h = out;                              // output 0: [T,B,H]
  float* out_emb = out + (size_t)T_ * B_ * H_;     // output 1: [T,B,H]

  char* ws = (char*)d_ws;
  const size_t RDY_BYTES = (size_t)L_ * NCH * FSTRIDE * 4;
  const size_t X0_BYTES = (size_t)T_ * B_ * H_ * 2;
  const size_t XR_BYTES = (size_t)L_ * NCH * RING * 16 * H_ * 2;
  const size_t WF_BYTES = (size_t)L_ * G4H_ * H_ * 2;
  int* rdyp = (int*)ws;
  _Float16* X0 = (_Float16*)(ws + RDY_BYTES);
  _Float16* XR = (_Float16*)(ws + RDY_BYTES + X0_BYTES);
  _Float16* Wif = (_Float16*)(ws + RDY_BYTES + X0_BYTES + XR_BYTES);
  _Float16* Whf = (_Float16*)(ws + RDY_BYTES + X0_BYTES + XR_BYTES + WF_BYTES);

  hipMemsetAsync(rdyp, 0, RDY_BYTES, stream);
  wconv_kernel<<<(L_ * G4H_ * H_ + 255) / 256, 256, 0, stream>>>(Wih, Whh, Wif, Whf);
  emb_kernel<<<T_ * B_, H_, 0, stream>>>(xids, emb, out_emb, X0);

  void* args[] = {(void*)&Wif, (void*)&Whf, (void*)&bih, (void*)&bhh,
                  (void*)&X0,  (void*)&XR,  (void*)&out_h, (void*)&rdyp};
  hipLaunchCooperativeKernel((void*)lstm_persist_kernel, dim3(L_ * NCH), dim3(512),
                             args, 0, stream);
}

// Round 5
// 1571.252 us; speedup vs baseline: 1.7360x; 1.7360x over previous
//
#include <hip/hip_runtime.h>

#define T_ 1024
#define B_ 128
#define H_ 128
#define L_ 20
#define G4H_ 512
#define NCH 8              // batch chunks of 16 rows
#define RING 64            // ring depth (steps) per (layer,chunk) channel
#define GRP 4              // publish granularity (steps)
#define FSTRIDE 32         // flag padding: 32 ints = 128 B per flag

typedef _Float16 f16x8 __attribute__((ext_vector_type(8)));
typedef _Float16 f16x4 __attribute__((ext_vector_type(4)));
typedef float f32x4 __attribute__((ext_vector_type(4)));

__device__ __forceinline__ float fast_sig(float x) {
  float e = __builtin_amdgcn_exp2f(-1.44269504f * x);
  return __builtin_amdgcn_rcpf(1.0f + e);
}
__device__ __forceinline__ float fast_tanh(float x) {
  float e = __builtin_amdgcn_exp2f(2.88539008f * x);  // e^{2x}
  return 1.0f - 2.0f * __builtin_amdgcn_rcpf(e + 1.0f);
}

// ---- device-scope (sc1) memory ops: serviced at LLC, NO L2 wb/inv ----
__device__ __forceinline__ int flag_ld(const int* p) {
  int r;
  asm volatile("global_load_dword %0, %1, off sc1\n\ts_waitcnt vmcnt(0)"
               : "=v"(r) : "v"(p) : "memory");
  return r;
}
__device__ __forceinline__ void flag_st(int* p, int v) {
  asm volatile("global_store_dword %0, %1, off sc1" :: "v"(p), "v"(v) : "memory");
}
__device__ __forceinline__ void xld_sc1(f16x4* d, const _Float16* p) {  // issue, no wait
  asm volatile("global_load_dwordx2 %0, %1, off sc1" : "=&v"(*d) : "v"(p) : "memory");
}
__device__ __forceinline__ void xld_plain(f16x4* d, const _Float16* p) {
  asm volatile("global_load_dwordx2 %0, %1, off" : "=&v"(*d) : "v"(p) : "memory");
}
__device__ __forceinline__ void st32_sc1(_Float16* p, f16x8 a, f16x8 b) {
  asm volatile("global_store_dwordx4 %0, %1, off sc1\n\t"
               "global_store_dwordx4 %0, %2, off offset:16 sc1"
               :: "v"(p), "v"(a), "v"(b) : "memory");
}

__global__ void wconv_kernel(const float* __restrict__ Wih, const float* __restrict__ Whh,
                             _Float16* __restrict__ Wif, _Float16* __restrict__ Whf) {
  int i = blockIdx.x * 256 + threadIdx.x;
  if (i < L_ * G4H_ * H_) {
    Wif[i] = (_Float16)Wih[i];
    Whf[i] = (_Float16)Whh[i];
  }
}

__global__ void emb_kernel(const int* __restrict__ xids, const float* __restrict__ emb,
                           float* __restrict__ out_emb, _Float16* __restrict__ X0) {
  int row = blockIdx.x;       // t*B + b
  int d = threadIdx.x;        // 0..127
  int tok = xids[row];
  float v = emb[(size_t)tok * H_ + d];
  out_emb[(size_t)row * H_ + d] = v;
  X0[(size_t)row * H_ + d] = (_Float16)v;
}

// Persistent wavefront-pipelined LSTM. One block per (layer, batch-chunk).
// R5: all cross-block traffic (ring data + flags) uses sc1 device-scope ops
// through the LLC — no agent-scope atomics, hence no buffer_wbl2/buffer_inv
// L2 flushes (R3/R4's 600+ MB/dispatch HBM writeback storm). Release order:
// sc1 data stores -> per-wave vmcnt(0) via __syncthreads -> sc1 flag store.
// x tile staged once per step through LDS (de-dups 8x per-wave ring reads).
__launch_bounds__(512, 2)
__global__ void lstm_persist_kernel(const _Float16* __restrict__ Wif,
                                    const _Float16* __restrict__ Whf,
                                    const float* __restrict__ bih,
                                    const float* __restrict__ bhh,
                                    const _Float16* __restrict__ X0,
                                    _Float16* __restrict__ XR,
                                    float* __restrict__ out_h,
                                    int* __restrict__ rdy) {
  const int l = blockIdx.x >> 3;
  const int chunk = blockIdx.x & 7;
  const int lane = threadIdx.x & 63;
  const int wave = threadIdx.x >> 6;
  const int lr = lane & 15;    // A-frag row / B-frag col / D col
  const int lhi = lane >> 4;   // k-group; D row group
  const int k0 = lhi * 8;
  const int ub = wave * 16;    // hidden slice base
  const int xrow = threadIdx.x >> 5;  // coop x-stage: 16 rows
  const int xseg = threadIdx.x & 31;  // 32 segs x 4 halves = 8B

  // ---- weight fragments in registers/AGPRs: W[j=G*128+ub+lr][kt*32+k0..+8]
  f16x8 wi[4][4], wh[4][4];
  float bias[4];
  {
    const _Float16* wip = Wif + (size_t)l * G4H_ * H_;
    const _Float16* whp = Whf + (size_t)l * G4H_ * H_;
#pragma unroll
    for (int G = 0; G < 4; ++G) {
      int j = G * 128 + ub + lr;
      bias[G] = bih[l * G4H_ + j] + bhh[l * G4H_ + j];
#pragma unroll
      for (int kt = 0; kt < 4; ++kt) {
        wi[G][kt] = *(const f16x8*)(wip + (size_t)j * H_ + kt * 32 + k0);
        wh[G][kt] = *(const f16x8*)(whp + (size_t)j * H_ + kt * 32 + k0);
      }
    }
  }

  float cst[4] = {0.f, 0.f, 0.f, 0.f};
  f16x8 hf[4], xf[4];

  __shared__ _Float16 hstage[GRP][16][136];  // h exchange + group publish stage
  __shared__ _Float16 xstage[2][16][136];    // double-buffered x tile

  const size_t tile16 = (size_t)16 * H_;  // 2048 elems = 4KB per step-slice
  const _Float16* ring_in =
      (l > 0) ? XR + (size_t)((l - 1) * NCH + chunk) * RING * tile16 : X0;
  _Float16* ring_out = XR + (size_t)(l * NCH + chunk) * RING * tile16;

  int* rin = rdy + ((l - 1) * NCH + chunk) * FSTRIDE;    // valid only if l>0
  int* rout = rdy + (l * NCH + chunk) * FSTRIDE;
  int* rcons = rdy + ((l + 1) * NCH + chunk) * FSTRIDE;  // valid only if l<L-1

  // per-thread x source address for step t (producer ring layout, row-major)
  auto xsrc = [&](int t) -> const _Float16* {
    return (l == 0) ? X0 + ((size_t)t * B_ + chunk * 16 + xrow) * H_ + xseg * 4
                    : ring_in + (size_t)(t & (RING - 1)) * tile16 + (size_t)xrow * H_ + xseg * 4;
  };

  int rin_cache = 0, rcons_cache = 0;  // flags are monotonic -> cached lower bounds

  for (int tg = 0; tg < T_; tg += GRP) {
    // ---- flag waits (wave 0 only; skipped when cache already satisfies) ----
    if (wave == 0) {
      if (l > 0 && rin_cache < tg + GRP) {
        int v;
        while ((v = flag_ld(rin)) < tg + GRP) __builtin_amdgcn_s_sleep(2);
        rin_cache = v;
      }
      if (l < L_ - 1) {
        int need = tg + 2 * GRP - RING;
        if (need > 0 && rcons_cache < need) {
          int v;
          while ((v = flag_ld(rcons)) < need) __builtin_amdgcn_s_sleep(2);
          rcons_cache = v;
        }
      }
    }
    __syncthreads();

    // ---- stage x(tg) into xstage[0] (tg is a multiple of GRP=4) ----
    {
      f16x4 xs;
      const _Float16* sp = xsrc(tg);
      if (l == 0) xld_plain(&xs, sp); else xld_sc1(&xs, sp);
      asm volatile("s_waitcnt vmcnt(0)" ::: "memory");
      *(f16x4*)&xstage[0][xrow][xseg * 4] = xs;
    }
    asm volatile("s_waitcnt lgkmcnt(0)" ::: "memory");
    __builtin_amdgcn_s_barrier();

#pragma unroll
    for (int ti = 0; ti < GRP; ++ti) {
      const int t = tg + ti;

      // h_{t-1} and x_t fragments from LDS (sealed by previous barrier)
      if (t > 0) {
        const int ps = (ti + GRP - 1) & (GRP - 1);
#pragma unroll
        for (int kt = 0; kt < 4; ++kt)
          hf[kt] = *(const f16x8*)&hstage[ps][lr][kt * 32 + k0];
      } else {
#pragma unroll
        for (int kt = 0; kt < 4; ++kt)
#pragma unroll
          for (int i = 0; i < 8; ++i) hf[kt][i] = (_Float16)0.0f;
      }
#pragma unroll
      for (int kt = 0; kt < 4; ++kt)
        xf[kt] = *(const f16x8*)&xstage[t & 1][lr][kt * 32 + k0];

      f32x4 ai[4], ah[4];
#pragma unroll
      for (int G = 0; G < 4; ++G) {
        float bv = bias[G];
        ai[G][0] = bv; ai[G][1] = bv; ai[G][2] = bv; ai[G][3] = bv;
        ah[G][0] = 0.f; ah[G][1] = 0.f; ah[G][2] = 0.f; ah[G][3] = 0.f;
      }
      // input GEMM
#pragma unroll
      for (int kt = 0; kt < 4; ++kt)
#pragma unroll
        for (int G = 0; G < 4; ++G)
          ai[G] = __builtin_amdgcn_mfma_f32_16x16x32_f16(xf[kt], wi[G][kt], ai[G], 0, 0, 0);

      // issue coop load of x(t+1) (8B/thread); floats over the hidden GEMM
      f16x4 xs;
      const bool pre = (ti + 1 < GRP);
      if (pre) {
        const _Float16* sp = xsrc(t + 1);
        if (l == 0) xld_plain(&xs, sp); else xld_sc1(&xs, sp);
      }

      // hidden GEMM
#pragma unroll
      for (int kt = 0; kt < 4; ++kt)
#pragma unroll
        for (int G = 0; G < 4; ++G)
          ah[G] = __builtin_amdgcn_mfma_f32_16x16x32_f16(hf[kt], wh[G][kt], ah[G], 0, 0, 0);

      // gates: lane has (b = chunk*16 + lhi*4+r, u = ub+lr)
      float hnew[4];
#pragma unroll
      for (int r = 0; r < 4; ++r) {
        float pi = ai[0][r] + ah[0][r];
        float pf = ai[1][r] + ah[1][r];
        float pg = ai[2][r] + ah[2][r];
        float po = ai[3][r] + ah[3][r];
        float iv = fast_sig(pi);
        float fv = fast_sig(pf);
        float gv = fast_tanh(pg);
        float ov = fast_sig(po);
        float c = fv * cst[r] + iv * gv;
        cst[r] = c;
        hnew[r] = ov * fast_tanh(c);
      }

      if (l == L_ - 1) {  // fp32 output, fire-and-forget
#pragma unroll
        for (int r = 0; r < 4; ++r)
          out_h[((size_t)t * B_ + chunk * 16 + lhi * 4 + r) * H_ + ub + lr] = hnew[r];
      }

      if (pre) {  // complete x(t+1) load, stage to the other buffer
        asm volatile("s_waitcnt vmcnt(0)" ::: "memory");
        *(f16x4*)&xstage[(t + 1) & 1][xrow][xseg * 4] = xs;
      }
#pragma unroll
      for (int r = 0; r < 4; ++r) hstage[ti][lhi * 4 + r][ub + lr] = (_Float16)hnew[r];

      asm volatile("s_waitcnt lgkmcnt(0)" ::: "memory");
      __builtin_amdgcn_s_barrier();
    }

    // ---- group-end publish: hstage -> ring via sc1 (write-through to LLC) ----
    if (l < L_ - 1) {
      const int tid = threadIdx.x;
      const int ti2 = tid >> 7;
      const int rem = tid & 127;
      const int row = rem >> 3;
      const int seg = rem & 7;
      _Float16* dst = ring_out + (size_t)((tg + ti2) & (RING - 1)) * tile16 +
                      (size_t)row * H_ + seg * 16;
      const f16x8* src = (const f16x8*)&hstage[ti2][row][seg * 16];
      st32_sc1(dst, src[0], src[1]);
    }

    // release: vmcnt(0) per wave inside __syncthreads -> all sc1 stores are
    // complete (at LLC) before any thread proceeds; then one flag store.
    __syncthreads();
    if (threadIdx.x == 0) flag_st(rout, tg + GRP);
  }
}

extern "C" void kernel_launch(void* const* d_in, const int* in_sizes, int n_in,
                              void* d_out, int out_size, void* d_ws, size_t ws_size,
                              hipStream_t stream) {
  const int* xids = (const int*)d_in[0];
  const float* emb = (const float*)d_in[1];
  const float* Wih = (const float*)d_in[2];
  const float* Whh = (const float*)d_in[3];
  const float* bih = (const float*)d_in[4];
  const float* bhh = (const float*)d_in[5];
  float* out = (float*)d_out;
  float* out_h = out;                              // output 0: [T,B,H]
  float* out_emb = out + (size_t)T_ * B_ * H_;     // output 1: [T,B,H]

  char* ws = (char*)d_ws;
  const size_t RDY_BYTES = (size_t)L_ * NCH * FSTRIDE * 4;
  const size_t X0_BYTES = (size_t)T_ * B_ * H_ * 2;
  const size_t XR_BYTES = (size_t)L_ * NCH * RING * 16 * H_ * 2;
  const size_t WF_BYTES = (size_t)L_ * G4H_ * H_ * 2;
  int* rdyp = (int*)ws;
  _Float16* X0 = (_Float16*)(ws + RDY_BYTES);
  _Float16* XR = (_Float16*)(ws + RDY_BYTES + X0_BYTES);
  _Float16* Wif = (_Float16*)(ws + RDY_BYTES + X0_BYTES + XR_BYTES);
  _Float16* Whf = (_Float16*)(ws + RDY_BYTES + X0_BYTES + XR_BYTES + WF_BYTES);

  hipMemsetAsync(rdyp, 0, RDY_BYTES, stream);
  wconv_kernel<<<(L_ * G4H_ * H_ + 255) / 256, 256, 0, stream>>>(Wih, Whh, Wif, Whf);
  emb_kernel<<<T_ * B_, H_, 0, stream>>>(xids, emb, out_emb, X0);

  void* args[] = {(void*)&Wif, (void*)&Whf, (void*)&bih, (void*)&bhh,
                  (void*)&X0,  (void*)&XR,  (void*)&out_h, (void*)&rdyp};
  hipLaunchCooperativeKernel((void*)lstm_persist_kernel, dim3(L_ * NCH), dim3(512),
                             args, 0, stream);
}

// Round 6
// 1568.206 us; speedup vs baseline: 1.7394x; 1.0019x over previous
//
#include <hip/hip_runtime.h>

#define T_ 1024
#define B_ 128
#define H_ 128
#define L_ 20
#define G4H_ 512
#define NCH 8              // batch chunks of 16 rows
#define RING 64            // ring depth (steps) per (layer,chunk) channel
#define GRP 4              // publish granularity (steps)
#define FSTRIDE 32         // flag padding: 32 ints = 128 B per flag

typedef _Float16 f16x8 __attribute__((ext_vector_type(8)));
typedef _Float16 f16x4 __attribute__((ext_vector_type(4)));
typedef float f32x4 __attribute__((ext_vector_type(4)));

__device__ __forceinline__ float fast_sig(float x) {
  float e = __builtin_amdgcn_exp2f(-1.44269504f * x);
  return __builtin_amdgcn_rcpf(1.0f + e);
}
__device__ __forceinline__ float fast_tanh(float x) {
  float e = __builtin_amdgcn_exp2f(2.88539008f * x);  // e^{2x}
  return 1.0f - 2.0f * __builtin_amdgcn_rcpf(e + 1.0f);
}

// ---- device-scope (sc1) memory ops: serviced at LLC, NO L2 wb/inv ----
__device__ __forceinline__ int flag_ld(const int* p) {
  int r;
  asm volatile("global_load_dword %0, %1, off sc1\n\ts_waitcnt vmcnt(0)"
               : "=v"(r) : "v"(p) : "memory");
  return r;
}
__device__ __forceinline__ void flag_st(int* p, int v) {
  asm volatile("global_store_dword %0, %1, off sc1" :: "v"(p), "v"(v) : "memory");
}
__device__ __forceinline__ void xld_sc1(f16x4* d, const _Float16* p) {  // issue only
  asm volatile("global_load_dwordx2 %0, %1, off sc1" : "=&v"(*d) : "v"(p) : "memory");
}
__device__ __forceinline__ void xld_plain(f16x4* d, const _Float16* p) {
  asm volatile("global_load_dwordx2 %0, %1, off" : "=&v"(*d) : "v"(p) : "memory");
}
__device__ __forceinline__ void st32_sc1(_Float16* p, f16x8 a, f16x8 b) {
  asm volatile("global_store_dwordx4 %0, %1, off sc1\n\t"
               "global_store_dwordx4 %0, %2, off offset:16 sc1"
               :: "v"(p), "v"(a), "v"(b) : "memory");
}

__global__ void wconv_kernel(const float* __restrict__ Wih, const float* __restrict__ Whh,
                             _Float16* __restrict__ Wif, _Float16* __restrict__ Whf) {
  int i = blockIdx.x * 256 + threadIdx.x;
  if (i < L_ * G4H_ * H_) {
    Wif[i] = (_Float16)Wih[i];
    Whf[i] = (_Float16)Whh[i];
  }
}

__global__ void emb_kernel(const int* __restrict__ xids, const float* __restrict__ emb,
                           float* __restrict__ out_emb, _Float16* __restrict__ X0) {
  int row = blockIdx.x;       // t*B + b
  int d = threadIdx.x;        // 0..127
  int tok = xids[row];
  float v = emb[(size_t)tok * H_ + d];
  out_emb[(size_t)row * H_ + d] = v;
  X0[(size_t)row * H_ + d] = (_Float16)v;
}

// Persistent wavefront-pipelined LSTM, R6: software-pipelined step.
//  - ai register pair carries bias + Wih·x_t computed one step AHEAD;
//    hidden GEMM accumulates into it (MFMA C-in), gates read it directly.
//  - x staged at distance 3: issue sc1 load x_{t+3} at step t, vmcnt+LDS
//    write at t+1 (xstage depth 4), fragments read at t+2.
//  - one raw s_barrier per step; publish + flags once per GRP group.
//  - consumer flag lead = tg+2*GRP (licenses the distance-3 prefetch).
__launch_bounds__(512, 2)
__global__ void lstm_persist_kernel(const _Float16* __restrict__ Wif,
                                    const _Float16* __restrict__ Whf,
                                    const float* __restrict__ bih,
                                    const float* __restrict__ bhh,
                                    const _Float16* __restrict__ X0,
                                    _Float16* __restrict__ XR,
                                    float* __restrict__ out_h,
                                    int* __restrict__ rdy) {
  const int l = blockIdx.x >> 3;
  const int chunk = blockIdx.x & 7;
  const int lane = threadIdx.x & 63;
  const int wave = threadIdx.x >> 6;
  const int lr = lane & 15;    // A-frag row / B-frag col / D col
  const int lhi = lane >> 4;   // k-group; D row group
  const int k0 = lhi * 8;
  const int ub = wave * 16;    // hidden slice base
  const int xrow = threadIdx.x >> 5;  // coop x-stage: 16 rows
  const int xseg = threadIdx.x & 31;  // 32 segs x 8B

  // ---- weight fragments (VGPR/AGPR): W[j=G*128+ub+lr][kt*32+k0..+8]
  f16x8 wi[4][4], wh[4][4];
  float bias[4];
  {
    const _Float16* wip = Wif + (size_t)l * G4H_ * H_;
    const _Float16* whp = Whf + (size_t)l * G4H_ * H_;
#pragma unroll
    for (int G = 0; G < 4; ++G) {
      int j = G * 128 + ub + lr;
      bias[G] = bih[l * G4H_ + j] + bhh[l * G4H_ + j];
#pragma unroll
      for (int kt = 0; kt < 4; ++kt) {
        wi[G][kt] = *(const f16x8*)(wip + (size_t)j * H_ + kt * 32 + k0);
        wh[G][kt] = *(const f16x8*)(whp + (size_t)j * H_ + kt * 32 + k0);
      }
    }
  }

  float cst[4] = {0.f, 0.f, 0.f, 0.f};
  f16x8 hf[4];
#pragma unroll
  for (int kt = 0; kt < 4; ++kt)
#pragma unroll
    for (int i = 0; i < 8; ++i) hf[kt][i] = (_Float16)0.0f;

  __shared__ _Float16 hstage[GRP][16][136];  // h exchange + group publish stage
  __shared__ _Float16 xstage[4][16][136];    // 4-deep x pipeline

  const size_t tile16 = (size_t)16 * H_;
  const _Float16* ring_in =
      (l > 0) ? XR + (size_t)((l - 1) * NCH + chunk) * RING * tile16 : X0;
  _Float16* ring_out = XR + (size_t)(l * NCH + chunk) * RING * tile16;

  int* rin = rdy + ((l - 1) * NCH + chunk) * FSTRIDE;
  int* rout = rdy + (l * NCH + chunk) * FSTRIDE;
  int* rcons = rdy + ((l + 1) * NCH + chunk) * FSTRIDE;

  auto xsrc = [&](int t) -> const _Float16* {
    return (l == 0) ? X0 + ((size_t)t * B_ + chunk * 16 + xrow) * H_ + xseg * 4
                    : ring_in + (size_t)(t & (RING - 1)) * tile16 + (size_t)xrow * H_ + xseg * 4;
  };

  int rin_cache = 0, rcons_cache = 0;

  // ---------- preamble: flags, stage x0..x2, compute ai(t=0) ----------
  if (wave == 0 && l > 0) {
    int tgt = 2 * GRP;  // covers x_0..x_{2*GRP-1} >= all prefetch in group 0
    int v;
    while ((v = flag_ld(rin)) < tgt) __builtin_amdgcn_s_sleep(2);
    rin_cache = v;
  }
  __syncthreads();
  {
    f16x4 a0, a1, a2;
    if (l == 0) { xld_plain(&a0, xsrc(0)); xld_plain(&a1, xsrc(1)); xld_plain(&a2, xsrc(2)); }
    else        { xld_sc1(&a0, xsrc(0));   xld_sc1(&a1, xsrc(1));   xld_sc1(&a2, xsrc(2)); }
    asm volatile("s_waitcnt vmcnt(0)" ::: "memory");
    *(f16x4*)&xstage[0][xrow][xseg * 4] = a0;
    *(f16x4*)&xstage[1][xrow][xseg * 4] = a1;
    *(f16x4*)&xstage[2][xrow][xseg * 4] = a2;
  }
  asm volatile("s_waitcnt lgkmcnt(0)" ::: "memory");
  __builtin_amdgcn_s_barrier();

  f32x4 ai[4];  // bias + Wih·x_t, computed one step ahead
  {
    f16x8 xf0[4];
#pragma unroll
    for (int kt = 0; kt < 4; ++kt) xf0[kt] = *(const f16x8*)&xstage[0][lr][kt * 32 + k0];
#pragma unroll
    for (int G = 0; G < 4; ++G) {
      float bv = bias[G];
      ai[G][0] = bv; ai[G][1] = bv; ai[G][2] = bv; ai[G][3] = bv;
    }
#pragma unroll
    for (int kt = 0; kt < 4; ++kt)
#pragma unroll
      for (int G = 0; G < 4; ++G)
        ai[G] = __builtin_amdgcn_mfma_f32_16x16x32_f16(xf0[kt], wi[G][kt], ai[G], 0, 0, 0);
  }

  f16x4 xs;               // in-flight x_{t+3} staging value
  bool xs_pending = false;

  // ---------- main loop ----------
  for (int t = 0; t < T_; ++t) {
    if ((t & (GRP - 1)) == 0 && t > 0) {  // group start: flag gates
      const int tg = t;
      if (wave == 0) {
        if (l > 0) {
          int tgt = tg + 2 * GRP; if (tgt > T_) tgt = T_;
          if (rin_cache < tgt) {
            int v;
            while ((v = flag_ld(rin)) < tgt) __builtin_amdgcn_s_sleep(2);
            rin_cache = v;
          }
        }
        if (l < L_ - 1) {
          int need = tg + 2 * GRP - RING;
          if (need > 0 && rcons_cache < need) {
            int v;
            while ((v = flag_ld(rcons)) < need) __builtin_amdgcn_s_sleep(2);
            rcons_cache = v;
          }
        }
      }
      __builtin_amdgcn_s_barrier();
    }

    // h_{t-1} fragments (sealed by last step's barrier)
    if (t > 0) {
      const int ps = (t - 1) & (GRP - 1);
#pragma unroll
      for (int kt = 0; kt < 4; ++kt)
        hf[kt] = *(const f16x8*)&hstage[ps][lr][kt * 32 + k0];
    }

    // hidden GEMM accumulates into ai -> full pre-activation
#pragma unroll
    for (int kt = 0; kt < 4; ++kt)
#pragma unroll
      for (int G = 0; G < 4; ++G)
        ai[G] = __builtin_amdgcn_mfma_f32_16x16x32_f16(hf[kt], wh[G][kt], ai[G], 0, 0, 0);

    // next-step input GEMM (independent of h_t; overlaps gates on MFMA pipe)
    const bool have_next = (t + 1 < T_);
    f32x4 ain[4];
    if (have_next) {
      f16x8 xfn[4];
#pragma unroll
      for (int kt = 0; kt < 4; ++kt)
        xfn[kt] = *(const f16x8*)&xstage[(t + 1) & 3][lr][kt * 32 + k0];
#pragma unroll
      for (int G = 0; G < 4; ++G) {
        float bv = bias[G];
        ain[G][0] = bv; ain[G][1] = bv; ain[G][2] = bv; ain[G][3] = bv;
      }
#pragma unroll
      for (int kt = 0; kt < 4; ++kt)
#pragma unroll
        for (int G = 0; G < 4; ++G)
          ain[G] = __builtin_amdgcn_mfma_f32_16x16x32_f16(xfn[kt], wi[G][kt], ain[G], 0, 0, 0);
    }

    // complete pending x stage (issued last step; ~1 step of latency cover)
    if (xs_pending) {
      asm volatile("s_waitcnt vmcnt(0)" ::: "memory");
      *(f16x4*)&xstage[(t + 2) & 3][xrow][xseg * 4] = xs;
    }
    // issue x_{t+3} (licensed by the tg+2*GRP flag lead)
    if (t + 3 < T_) {
      const _Float16* sp = xsrc(t + 3);
      if (l == 0) xld_plain(&xs, sp); else xld_sc1(&xs, sp);
      xs_pending = true;
    } else {
      xs_pending = false;
    }

    // gates: lane has (b = chunk*16 + lhi*4+r, u = ub+lr)
    float hnew[4];
#pragma unroll
    for (int r = 0; r < 4; ++r) {
      float iv = fast_sig(ai[0][r]);
      float fv = fast_sig(ai[1][r]);
      float gv = fast_tanh(ai[2][r]);
      float ov = fast_sig(ai[3][r]);
      float c = fv * cst[r] + iv * gv;
      cst[r] = c;
      hnew[r] = ov * fast_tanh(c);
    }

    if (l == L_ - 1) {  // fp32 output, fire-and-forget
#pragma unroll
      for (int r = 0; r < 4; ++r)
        out_h[((size_t)t * B_ + chunk * 16 + lhi * 4 + r) * H_ + ub + lr] = hnew[r];
    }

#pragma unroll
    for (int r = 0; r < 4; ++r) hstage[t & (GRP - 1)][lhi * 4 + r][ub + lr] = (_Float16)hnew[r];

    if (have_next) {
#pragma unroll
      for (int G = 0; G < 4; ++G) ai[G] = ain[G];
    }

    asm volatile("s_waitcnt lgkmcnt(0)" ::: "memory");
    __builtin_amdgcn_s_barrier();

    if ((t & (GRP - 1)) == GRP - 1) {  // group end: publish + flag
      const int tg = t & ~(GRP - 1);
      if (l < L_ - 1) {
        const int tid = threadIdx.x;
        const int ti2 = tid >> 7;
        const int rem = tid & 127;
        const int row = rem >> 3;
        const int seg = rem & 7;
        _Float16* dst = ring_out + (size_t)((tg + ti2) & (RING - 1)) * tile16 +
                        (size_t)row * H_ + seg * 16;
        const f16x8* src = (const f16x8*)&hstage[ti2][row][seg * 16];
        st32_sc1(dst, src[0], src[1]);
      }
      __syncthreads();  // per-wave vmcnt(0): sc1 stores complete at LLC
      if (threadIdx.x == 0) flag_st(rout, t + 1);
    }
  }
}

extern "C" void kernel_launch(void* const* d_in, const int* in_sizes, int n_in,
                              void* d_out, int out_size, void* d_ws, size_t ws_size,
                              hipStream_t stream) {
  const int* xids = (const int*)d_in[0];
  const float* emb = (const float*)d_in[1];
  const float* Wih = (const float*)d_in[2];
  const float* Whh = (const float*)d_in[3];
  const float* bih = (const float*)d_in[4];
  const float* bhh = (const float*)d_in[5];
  float* out = (float*)d_out;
  float* out_h = out;                              // output 0: [T,B,H]
  float* out_emb = out + (size_t)T_ * B_ * H_;     // output 1: [T,B,H]

  char* ws = (char*)d_ws;
  const size_t RDY_BYTES = (size_t)L_ * NCH * FSTRIDE * 4;
  const size_t X0_BYTES = (size_t)T_ * B_ * H_ * 2;
  const size_t XR_BYTES = (size_t)L_ * NCH * RING * 16 * H_ * 2;
  const size_t WF_BYTES = (size_t)L_ * G4H_ * H_ * 2;
  int* rdyp = (int*)ws;
  _Float16* X0 = (_Float16*)(ws + RDY_BYTES);
  _Float16* XR = (_Float16*)(ws + RDY_BYTES + X0_BYTES);
  _Float16* Wif = (_Float16*)(ws + RDY_BYTES + X0_BYTES + XR_BYTES);
  _Float16* Whf = (_Float16*)(ws + RDY_BYTES + X0_BYTES + XR_BYTES + WF_BYTES);

  hipMemsetAsync(rdyp, 0, RDY_BYTES, stream);
  wconv_kernel<<<(L_ * G4H_ * H_ + 255) / 256, 256, 0, stream>>>(Wih, Whh, Wif, Whf);
  emb_kernel<<<T_ * B_, H_, 0, stream>>>(xids, emb, out_emb, X0);

  void* args[] = {(void*)&Wif, (void*)&Whf, (void*)&bih, (void*)&bhh,
                  (void*)&X0,  (void*)&XR,  (void*)&out_h, (void*)&rdyp};
  hipLaunchCooperativeKernel((void*)lstm_persist_kernel, dim3(L_ * NCH), dim3(512),
                             args, 0, stream);
}

// Round 7
// 1510.538 us; speedup vs baseline: 1.8058x; 1.0382x over previous
//
#include <hip/hip_runtime.h>

#define T_ 1024
#define B_ 128
#define H_ 128
#define L_ 20
#define G4H_ 512
#define NCH 8              // batch chunks of 16 rows
#define RING 64            // ring depth (steps) per (layer,chunk) channel
#define GRP 4              // publish granularity (steps)
#define FSTRIDE 32         // flag padding: 32 ints = 128 B per flag
#define STR 136            // LDS row stride in f16 (272 B, 16B-aligned)

typedef _Float16 f16x8 __attribute__((ext_vector_type(8)));
typedef _Float16 f16x4 __attribute__((ext_vector_type(4)));
typedef float f32x4 __attribute__((ext_vector_type(4)));

__device__ __forceinline__ float fast_sig(float x) {
  float e = __builtin_amdgcn_exp2f(-1.44269504f * x);
  return __builtin_amdgcn_rcpf(1.0f + e);
}
__device__ __forceinline__ float fast_tanh(float x) {
  float e = __builtin_amdgcn_exp2f(2.88539008f * x);  // e^{2x}
  return 1.0f - 2.0f * __builtin_amdgcn_rcpf(e + 1.0f);
}

#define VMW(n) asm volatile("s_waitcnt vmcnt(" #n ")" ::: "memory")
#define LGKM0() asm volatile("s_waitcnt lgkmcnt(0)" ::: "memory")

// ---- device-scope (sc1) memory ops: serviced at LLC, NO L2 wb/inv ----
__device__ __forceinline__ int flag_ld(const int* p) {
  int r;
  asm volatile("global_load_dword %0, %1, off sc1\n\ts_waitcnt vmcnt(0)"
               : "=v"(r) : "v"(p) : "memory");
  return r;
}
__device__ __forceinline__ void flag_st(int* p, int v) {
  asm volatile("global_store_dword %0, %1, off sc1" :: "v"(p), "v"(v) : "memory");
}
__device__ __forceinline__ void xld_sc1(f16x4* d, const _Float16* p) {  // issue only
  asm volatile("global_load_dwordx2 %0, %1, off sc1" : "=&v"(*d) : "v"(p) : "memory");
}
__device__ __forceinline__ void xld_plain(f16x4* d, const _Float16* p) {
  asm volatile("global_load_dwordx2 %0, %1, off" : "=&v"(*d) : "v"(p) : "memory");
}
__device__ __forceinline__ void st32_sc1(_Float16* p, f16x8 a, f16x8 b) {
  asm volatile("global_store_dwordx4 %0, %1, off sc1\n\t"
               "global_store_dwordx4 %0, %2, off offset:16 sc1"
               :: "v"(p), "v"(a), "v"(b) : "memory");
}

__global__ void wconv_kernel(const float* __restrict__ Wih, const float* __restrict__ Whh,
                             _Float16* __restrict__ Wif, _Float16* __restrict__ Whf) {
  int i = blockIdx.x * 256 + threadIdx.x;
  if (i < L_ * G4H_ * H_) {
    Wif[i] = (_Float16)Wih[i];
    Whf[i] = (_Float16)Whh[i];
  }
}

__global__ void emb_kernel(const int* __restrict__ xids, const float* __restrict__ emb,
                           float* __restrict__ out_emb, _Float16* __restrict__ X0) {
  int row = blockIdx.x;       // t*B + b
  int d = threadIdx.x;        // 0..127
  int tok = xids[row];
  float v = emb[(size_t)tok * H_ + d];
  out_emb[(size_t)row * H_ + d] = v;
  X0[(size_t)row * H_ + d] = (_Float16)v;
}

// Persistent wavefront-pipelined LSTM, R7:
//  - SWAPPED MFMA operands: W is the A-operand (same regs as before — A and B
//    share the lane layout), h/x the B-operand. D = [hidden][batch], so each
//    lane's 4 outputs are 4 consecutive hidden -> h-exchange write is ONE
//    ds_write_b64, out_h is one dwordx4, bias is a float4 per gate.
//  - deferred flag publish: boundary entering group g issues pub(g-1); its
//    completion is certified at the NEXT boundary via counted vmcnt(4), then
//    flag = 4*(g-1) (data certified through group g-2). No vmcnt(0) drains.
//  - per-step x staging with counted vmcnt(3/1); prefetch distance 4.
__launch_bounds__(512, 2)
__global__ void lstm_persist_kernel(const _Float16* __restrict__ Wif,
                                    const _Float16* __restrict__ Whf,
                                    const float* __restrict__ bih,
                                    const float* __restrict__ bhh,
                                    const _Float16* __restrict__ X0,
                                    _Float16* __restrict__ XR,
                                    float* __restrict__ out_h,
                                    int* __restrict__ rdy) {
  const int l = blockIdx.x >> 3;
  const int chunk = blockIdx.x & 7;
  const int lane = threadIdx.x & 63;
  const int wave = threadIdx.x >> 6;
  const int lr = lane & 15;    // A row (=hidden j) / B col (=batch b) / D col
  const int lhi = lane >> 4;   // k-subgroup; D row group
  const int ub = wave * 16;    // hidden slice base
  const int xrow = threadIdx.x >> 5;  // coop x-stage: 16 rows (batch)
  const int xseg = threadIdx.x & 31;  // 32 segs x 8B

  // ---- weight fragments (VGPR/AGPR): lane holds W[j=G*128+ub+lr][kt*32+lhi*8..+8]
  f16x8 wi[4][4], wh[4][4];
  f32x4 bias4[4];
  {
    const _Float16* wip = Wif + (size_t)l * G4H_ * H_;
    const _Float16* whp = Whf + (size_t)l * G4H_ * H_;
#pragma unroll
    for (int G = 0; G < 4; ++G) {
      int j = G * 128 + ub + lr;
#pragma unroll
      for (int kt = 0; kt < 4; ++kt) {
        wi[G][kt] = *(const f16x8*)(wip + (size_t)j * H_ + kt * 32 + lhi * 8);
        wh[G][kt] = *(const f16x8*)(whp + (size_t)j * H_ + kt * 32 + lhi * 8);
      }
      // D row = hidden j = G*128 + ub + lhi*4 + r  -> bias as float4 over r
      int jb = G * 128 + ub + lhi * 4;
      bias4[G] = *(const f32x4*)&bih[l * G4H_ + jb];
      bias4[G] += *(const f32x4*)&bhh[l * G4H_ + jb];
    }
  }

  float cst[4] = {0.f, 0.f, 0.f, 0.f};
  f16x8 hf[4];

  __shared__ _Float16 hstage[GRP][16][STR];  // [b][hidden] h exchange + publish
  __shared__ _Float16 xstage[4][16][STR];    // [b][k] 4-deep x pipeline

  const size_t tile16 = (size_t)16 * H_;  // 2048 f16 = 4KB per step-slice
  const _Float16* ring_in =
      (l > 0) ? XR + (size_t)((l - 1) * NCH + chunk) * RING * tile16 : X0;
  _Float16* ring_out = XR + (size_t)(l * NCH + chunk) * RING * tile16;

  int* rin = rdy + ((l - 1) * NCH + chunk) * FSTRIDE;
  int* rout = rdy + (l * NCH + chunk) * FSTRIDE;
  int* rcons = rdy + ((l + 1) * NCH + chunk) * FSTRIDE;

  auto xsrc = [&](int t) -> const _Float16* {
    return (l == 0) ? X0 + ((size_t)t * B_ + chunk * 16 + xrow) * H_ + xseg * 4
                    : ring_in + (size_t)(t & (RING - 1)) * tile16 + (size_t)xrow * H_ + xseg * 4;
  };

  int rin_cache = 0, rcons_cache = 0;

  // ---------- prologue: initial flag, stage x0..x3, compute a0 = bias+Wih·x0
  if (wave == 0 && l > 0) {
    int v;
    while ((v = flag_ld(rin)) < 2 * GRP) __builtin_amdgcn_s_sleep(2);
    rin_cache = v;
  }
  __syncthreads();
  {
    f16x4 a0, a1, a2, a3;
    if (l == 0) { xld_plain(&a0, xsrc(0)); xld_plain(&a1, xsrc(1));
                  xld_plain(&a2, xsrc(2)); xld_plain(&a3, xsrc(3)); }
    else        { xld_sc1(&a0, xsrc(0)); xld_sc1(&a1, xsrc(1));
                  xld_sc1(&a2, xsrc(2)); xld_sc1(&a3, xsrc(3)); }
    VMW(0);
    *(f16x4*)&xstage[0][xrow][xseg * 4] = a0;
    *(f16x4*)&xstage[1][xrow][xseg * 4] = a1;
    *(f16x4*)&xstage[2][xrow][xseg * 4] = a2;
    *(f16x4*)&xstage[3][xrow][xseg * 4] = a3;
  }
  LGKM0();
  __builtin_amdgcn_s_barrier();

  f32x4 a0[4], a1[4];
  {
    f16x8 xf0[4];
#pragma unroll
    for (int kt = 0; kt < 4; ++kt)
      xf0[kt] = *(const f16x8*)&xstage[0][lr][kt * 32 + lhi * 8];
#pragma unroll
    for (int G = 0; G < 4; ++G) a0[G] = bias4[G];
#pragma unroll
    for (int kt = 0; kt < 4; ++kt)
#pragma unroll
      for (int G = 0; G < 4; ++G)
        a0[G] = __builtin_amdgcn_mfma_f32_16x16x32_f16(wi[G][kt], xf0[kt], a0[G], 0, 0, 0);
  }

  f16x4 xsp[2];  // in-flight x loads, parity-indexed (static per STEP)

// One LSTM step. ti is a literal 0..3; AC holds bias+Wih·x_t (becomes the full
// preactivation after the hidden GEMM); AN is filled with bias+Wih·x_{t+1}.
#define STEP(ti, AC, AN)                                                         \
  {                                                                              \
    const int t = tg + (ti);                                                     \
    if (t > 0) {                                                                 \
      _Pragma("unroll")                                                          \
      for (int kt = 0; kt < 4; ++kt)                                             \
        hf[kt] = *(const f16x8*)&hstage[((ti) + 3) & 3][lr][kt * 32 + lhi * 8];  \
      _Pragma("unroll")                                                          \
      for (int kt = 0; kt < 4; ++kt)                                             \
        _Pragma("unroll")                                                        \
        for (int G = 0; G < 4; ++G)                                              \
          AC[G] = __builtin_amdgcn_mfma_f32_16x16x32_f16(wh[G][kt], hf[kt], AC[G], 0, 0, 0); \
    }                                                                            \
    if (t + 1 < T_) {                                                            \
      f16x8 xfn[4];                                                              \
      _Pragma("unroll")                                                          \
      for (int kt = 0; kt < 4; ++kt)                                             \
        xfn[kt] = *(const f16x8*)&xstage[((ti) + 1) & 3][lr][kt * 32 + lhi * 8]; \
      _Pragma("unroll")                                                          \
      for (int G = 0; G < 4; ++G) AN[G] = bias4[G];                              \
      _Pragma("unroll")                                                          \
      for (int kt = 0; kt < 4; ++kt)                                             \
        _Pragma("unroll")                                                        \
        for (int G = 0; G < 4; ++G)                                              \
          AN[G] = __builtin_amdgcn_mfma_f32_16x16x32_f16(wi[G][kt], xfn[kt], AN[G], 0, 0, 0); \
    }                                                                            \
    if (t >= 2 && t + 2 < T_) { /* complete x(t+2), issued at t-2 */             \
      if (t >= T_ - 8) { VMW(0); }                                               \
      else if ((ti) < 2) { VMW(3); }                                             \
      else if (l == L_ - 1) { VMW(3); }                                          \
      else { VMW(1); }                                                           \
      *(f16x4*)&xstage[((ti) + 2) & 3][xrow][xseg * 4] = xsp[(ti) & 1];          \
    }                                                                            \
    if (t + 4 < T_) { /* issue x(t+4) into the just-freed parity reg */          \
      const _Float16* sp = xsrc(t + 4);                                          \
      if (l == 0) xld_plain(&xsp[(ti) & 1], sp); else xld_sc1(&xsp[(ti) & 1], sp); \
    }                                                                            \
    float hnew[4];                                                               \
    _Pragma("unroll")                                                            \
    for (int r = 0; r < 4; ++r) {                                                \
      float iv = fast_sig(AC[0][r]);                                             \
      float fv = fast_sig(AC[1][r]);                                             \
      float gv = fast_tanh(AC[2][r]);                                            \
      float ov = fast_sig(AC[3][r]);                                             \
      float c = fv * cst[r] + iv * gv;                                           \
      cst[r] = c;                                                                \
      hnew[r] = ov * fast_tanh(c);                                               \
    }                                                                            \
    {                                                                            \
      f16x4 hp;                                                                  \
      _Pragma("unroll")                                                          \
      for (int r = 0; r < 4; ++r) hp[r] = (_Float16)hnew[r];                     \
      *(f16x4*)&hstage[(ti)][lr][ub + lhi * 4] = hp;                             \
    }                                                                            \
    if (l == L_ - 1) {                                                           \
      f32x4 ov4;                                                                 \
      _Pragma("unroll")                                                          \
      for (int r = 0; r < 4; ++r) ov4[r] = hnew[r];                              \
      *(f32x4*)&out_h[((size_t)t * B_ + chunk * 16 + lr) * H_ + ub + lhi * 4] = ov4; \
    }                                                                            \
    LGKM0();                                                                     \
    __builtin_amdgcn_s_barrier();                                                \
  }

  // ---------- main loop ----------
  for (int tg = 0; tg < T_; tg += GRP) {
    if (tg > 0) {  // boundary entering group g = tg/4
      if (wave == 0) {
        if (l > 0) {
          int tgt = tg + 2 * GRP; if (tgt > T_) tgt = T_;
          if (rin_cache < tgt) {
            int v;
            while ((v = flag_ld(rin)) < tgt) __builtin_amdgcn_s_sleep(2);
            rin_cache = v;
          }
        }
        if (l < L_ - 1) {
          int need = tg - 68;
          if (need > 0 && rcons_cache < need) {
            int v;
            while ((v = flag_ld(rcons)) < need) __builtin_amdgcn_s_sleep(2);
            rcons_cache = v;
          }
        }
      }
      VMW(4);                        // pub(g-2) of my wave complete (4 x-loads newer)
      __builtin_amdgcn_s_barrier();  // all waves' pub(g-2) done + flags checked
      if (threadIdx.x == 0) flag_st(rout, tg - GRP);  // certify data <= group g-2
      if (l < L_ - 1) {              // issue pub(g-1) from hstage
        const int tid = threadIdx.x;
        const int ti2 = tid >> 7;
        const int rem = tid & 127;
        const int row = rem >> 3;
        const int seg = rem & 7;
        const f16x8 s0 = *(const f16x8*)&hstage[ti2][row][seg * 16];
        const f16x8 s1 = *(const f16x8*)&hstage[ti2][row][seg * 16 + 8];
        _Float16* dst = ring_out + (size_t)((tg - GRP + ti2) & (RING - 1)) * tile16 +
                        (size_t)row * H_ + seg * 16;
        st32_sc1(dst, s0, s1);
      }
      LGKM0();                       // publish LDS reads done before overwrite
      __builtin_amdgcn_s_barrier();
    }
    STEP(0, a0, a1)
    STEP(1, a1, a0)
    STEP(2, a0, a1)
    STEP(3, a1, a0)
  }

  // ---------- epilogue: publish last group, final flag ----------
  if (l < L_ - 1) {
    const int tid = threadIdx.x;
    const int ti2 = tid >> 7;
    const int rem = tid & 127;
    const int row = rem >> 3;
    const int seg = rem & 7;
    const f16x8 s0 = *(const f16x8*)&hstage[ti2][row][seg * 16];
    const f16x8 s1 = *(const f16x8*)&hstage[ti2][row][seg * 16 + 8];
    _Float16* dst = ring_out + (size_t)((T_ - GRP + ti2) & (RING - 1)) * tile16 +
                    (size_t)row * H_ + seg * 16;
    st32_sc1(dst, s0, s1);
  }
  __syncthreads();  // full drain (vmcnt 0): pub(254)+pub(255) complete at LLC
  if (threadIdx.x == 0) flag_st(rout, T_);  // certifies everything
}

extern "C" void kernel_launch(void* const* d_in, const int* in_sizes, int n_in,
                              void* d_out, int out_size, void* d_ws, size_t ws_size,
                              hipStream_t stream) {
  const int* xids = (const int*)d_in[0];
  const float* emb = (const float*)d_in[1];
  const float* Wih = (const float*)d_in[2];
  const float* Whh = (const float*)d_in[3];
  const float* bih = (const float*)d_in[4];
  const float* bhh = (const float*)d_in[5];
  float* out = (float*)d_out;
  float* out_h = out;                              // output 0: [T,B,H]
  float* out_emb = out + (size_t)T_ * B_ * H_;     // output 1: [T,B,H]

  char* ws = (char*)d_ws;
  const size_t RDY_BYTES = (size_t)L_ * NCH * FSTRIDE * 4;
  const size_t X0_BYTES = (size_t)T_ * B_ * H_ * 2;
  const size_t XR_BYTES = (size_t)L_ * NCH * RING * 16 * H_ * 2;
  const size_t WF_BYTES = (size_t)L_ * G4H_ * H_ * 2;
  int* rdyp = (int*)ws;
  _Float16* X0 = (_Float16*)(ws + RDY_BYTES);
  _Float16* XR = (_Float16*)(ws + RDY_BYTES + X0_BYTES);
  _Float16* Wif = (_Float16*)(ws + RDY_BYTES + X0_BYTES + XR_BYTES);
  _Float16* Whf = (_Float16*)(ws + RDY_BYTES + X0_BYTES + XR_BYTES + WF_BYTES);

  hipMemsetAsync(rdyp, 0, RDY_BYTES, stream);
  wconv_kernel<<<(L_ * G4H_ * H_ + 255) / 256, 256, 0, stream>>>(Wih, Whh, Wif, Whf);
  emb_kernel<<<T_ * B_, H_, 0, stream>>>(xids, emb, out_emb, X0);

  void* args[] = {(void*)&Wif, (void*)&Whf, (void*)&bih, (void*)&bhh,
                  (void*)&X0,  (void*)&XR,  (void*)&out_h, (void*)&rdyp};
  hipLaunchCooperativeKernel((void*)lstm_persist_kernel, dim3(L_ * NCH), dim3(512),
                             args, 0, stream);
}